// Round 14
// baseline (132.477 us; speedup 1.0000x reference)
//
#include <hip/hip_runtime.h>
#include <hip/hip_bf16.h>
#include <stdint.h>

// Problem constants
#define TSEQ   2048
#define DMODEL 1024
#define NHEAD  16
#define HDIM   64

typedef __attribute__((ext_vector_type(8))) __bf16 bf16x8;
typedef __attribute__((ext_vector_type(4))) float f32x4;
typedef __attribute__((ext_vector_type(8))) unsigned short u16x8;

// log2(e)/8 : folds the 1/sqrt(64) logit scale into exp2 (applied to Q in gemm1)
#define SC_LOG2E 0.18033688011112042f

#if __has_builtin(__builtin_amdgcn_exp2f)
#define EXP2F(x) __builtin_amdgcn_exp2f(x)
#else
#define EXP2F(x) __expf(0.6931471805599453f * (x))
#endif

__device__ __forceinline__ unsigned short f2bf(float f) {
    __hip_bfloat16 h = __float2bfloat16(f);
    return __builtin_bit_cast(unsigned short, h);
}
__device__ __forceinline__ float bf2f(unsigned short u) {
    union { unsigned int i; float f; } v;
    v.i = ((unsigned int)u) << 16;
    return v.f;
}
__device__ __forceinline__ unsigned int cvtpk_bf16(float lo, float hi) {
    unsigned int r;
    asm("v_cvt_pk_bf16_f32 %0, %1, %2" : "=v"(r) : "v"(lo), "v"(hi));
    return r;
}

__device__ __forceinline__ void gld_lds16(const void* g, void* s) {
    __builtin_amdgcn_global_load_lds(
        (__attribute__((address_space(1))) void*)(void*)g,
        (__attribute__((address_space(3))) void*)s, 16, 0, 0);
}

// ---------------------------------------------------------------------------
// fused fp32 -> bf16 cast for x, w_in, w_out (one launch)
// ---------------------------------------------------------------------------
#define NX4  (4096 * 1024 / 4)
#define NWI4 (3072 * 1024 / 4)
#define NWO4 (1024 * 1024 / 4)
__global__ void cast3_kernel(const float* __restrict__ x,
                             const float* __restrict__ wi,
                             const float* __restrict__ wo,
                             unsigned short* __restrict__ ox,
                             unsigned short* __restrict__ owi,
                             unsigned short* __restrict__ owo) {
    int i = blockIdx.x * blockDim.x + threadIdx.x;
    const float* s;
    unsigned short* d;
    int off;
    if (i < NX4)              { s = x;  d = ox;  off = i; }
    else if (i < NX4 + NWI4)  { s = wi; d = owi; off = i - NX4; }
    else                      { s = wo; d = owo; off = i - NX4 - NWI4; }
    float4 v = ((const float4*)s)[off];
    ushort4 u;
    u.x = f2bf(v.x); u.y = f2bf(v.y); u.z = f2bf(v.z); u.w = f2bf(v.w);
    ((ushort4*)d)[off] = u;
}

// ---------------------------------------------------------------------------
// GEMM: C[m,n] = sum_k A[m,k] * B[n,k]   (A:[M,K] bf16, B:[N,K] bf16)
// BK=64, FRAGMENT-ORDER LDS staging: slot c = tid+j*256 -> rb=c>>7,
// kk=(c>>6)&1, l=c&63 sources A[rb*16+(l&15)][kt + kk*32 + (l>>4)*8].
// Fragment reads are then per-lane-contiguous b128 (conflict-free), fixing
// the 9.4M-cycle 16-way bank conflict of row-major [128][64] (R13 PMC).
// MODE 0 (QKV GEMM, N=3072): bn<8 -> Q stored *SC_LOG2E; bn in [8,16) -> K
//   plain; bn in [16,24) -> V written TRANSPOSED to vtg + colsums to ts.
// MODE 1 (out GEMM): f32 store to C.
// ---------------------------------------------------------------------------
template<int MODE>
__global__ __launch_bounds__(256, 3)
void gemm_bt(const unsigned short* __restrict__ A,
             const unsigned short* __restrict__ B,
             void* __restrict__ C, int M, int N, int K,
             unsigned short* __restrict__ vtg,
             float* __restrict__ ts) {
    (void)M;
    __shared__ unsigned short As[128 * 64];
    __shared__ unsigned short Bs[128 * 64];
    const int tid = threadIdx.x;
    const int nb = N >> 7;
    const int bm = blockIdx.x / nb;
    const int bn = blockIdx.x % nb;
    const int w  = tid >> 6, l = tid & 63;
    const int wr = w >> 1,  wc = w & 1;
    const int lr = l & 15,  lg = l >> 4;

    f32x4 acc[4][4] = {};

    const unsigned short* Ab = A + (size_t)bm * 128 * K;
    const unsigned short* Bb = B + (size_t)bn * 128 * K;

    // fragment-order staging source pointers (kt added in the loop)
    const unsigned short* asrc[4];
    const unsigned short* bsrc[4];
#pragma unroll
    for (int j = 0; j < 4; j++) {
        const int c  = tid + j * 256;
        const int rb = c >> 7, kk = (c >> 6) & 1, ll = c & 63;
        const size_t row = (size_t)(rb * 16 + (ll & 15));
        const int col = kk * 32 + (ll >> 4) * 8;
        asrc[j] = Ab + row * K + col;
        bsrc[j] = Bb + row * K + col;
    }

    for (int kt = 0; kt < K; kt += 64) {
        __syncthreads();
#pragma unroll
        for (int j = 0; j < 4; j++)
            gld_lds16(asrc[j] + kt, As + (tid + j * 256) * 8);
#pragma unroll
        for (int j = 0; j < 4; j++)
            gld_lds16(bsrc[j] + kt, Bs + (tid + j * 256) * 8);
        __syncthreads();

#pragma unroll
        for (int kk = 0; kk < 2; kk++) {
            bf16x8 af[4], bfr[4];
#pragma unroll
            for (int i = 0; i < 4; i++)
                af[i] = *(const bf16x8*)(As + (((wr * 4 + i) * 2 + kk) * 64 + l) * 8);
#pragma unroll
            for (int i = 0; i < 4; i++)
                bfr[i] = *(const bf16x8*)(Bs + (((wc * 4 + i) * 2 + kk) * 64 + l) * 8);
#pragma unroll
            for (int mi = 0; mi < 4; mi++)
#pragma unroll
                for (int ni = 0; ni < 4; ni++)
                    acc[mi][ni] = __builtin_amdgcn_mfma_f32_16x16x32_bf16(
                        af[mi], bfr[ni], acc[mi][ni], 0, 0, 0);
        }
    }

    const int row0 = bm * 128 + wr * 64;
    const int col0 = bn * 128 + wc * 64;

    if (MODE == 0 && bn >= 16) {
        // ---- fused V transpose + column sums ----
        const int h     = (bn - 16) * 2 + wc;
        const int krow0 = row0;                 // wave's 64 token rows
        const int bb    = krow0 >> 11;
        const int kloc0 = krow0 & 2047;
        const int bh    = bb * 16 + h;
        const int t     = kloc0 >> 6;
#pragma unroll
        for (int ni = 0; ni < 4; ni++) {
            const size_t dbase = ((size_t)(bh * 64 + ni * 16 + lr)) * TSEQ;
#pragma unroll
            for (int mi = 0; mi < 4; mi++) {
                uint2 pk;
                pk.x = cvtpk_bf16(acc[mi][ni][0], acc[mi][ni][1]);
                pk.y = cvtpk_bf16(acc[mi][ni][2], acc[mi][ni][3]);
                *(uint2*)(vtg + dbase + kloc0 + mi * 16 + lg * 4) = pk;
            }
        }
#pragma unroll
        for (int ni = 0; ni < 4; ni++) {
            float sum = 0.f;
#pragma unroll
            for (int mi = 0; mi < 4; mi++)
#pragma unroll
                for (int r = 0; r < 4; r++) sum += acc[mi][ni][r];
            sum += __shfl_xor(sum, 16);
            sum += __shfl_xor(sum, 32);
            if (lg == 0)
                ts[((size_t)bh * 32 + t) * 64 + ni * 16 + lr] = sum;
        }
        return;
    }

    const float qsc = (MODE == 0 && bn < 8) ? SC_LOG2E : 1.0f;
#pragma unroll
    for (int mi = 0; mi < 4; mi++)
#pragma unroll
        for (int ni = 0; ni < 4; ni++)
#pragma unroll
            for (int r = 0; r < 4; r++) {
                const int row = row0 + mi * 16 + lg * 4 + r;
                const int col = col0 + ni * 16 + lr;
                if (MODE == 1)
                    ((float*)C)[(size_t)row * N + col] = acc[mi][ni][r];
                else
                    ((unsigned short*)C)[(size_t)row * N + col] =
                        f2bf(acc[mi][ni][r] * qsc);
            }
}

// ---------------------------------------------------------------------------
// Attention v10 (R10-verified, FROZEN): consecutive strip pairs, 4-wave
// blocks, dbuf LDS K/V^T, plain __syncthreads, swapped QK^T
// (S^T = mfma(K,Q): lane holds q=lr, k=f*16+lg*4+r), cvt_pk P-pack,
// lane-local rsum, vsuf folded in epilogue.
// ---------------------------------------------------------------------------
__global__ __launch_bounds__(256, 2)
void attn_kernel(const unsigned short* __restrict__ qkv,
                 const unsigned short* __restrict__ vtg,
                 const float* __restrict__ ts,
                 unsigned short* __restrict__ out) {
    __shared__ __attribute__((aligned(16))) unsigned short Ks[2][4096];
    __shared__ __attribute__((aligned(16))) unsigned short Vs[2][4096];
    __shared__ __attribute__((aligned(16))) unsigned short Pl[4][32 * 72];

    const int tid = threadIdx.x;
    const int w = tid >> 6, l = tid & 63, lr = l & 15, lg = l >> 4;
    const int bid = blockIdx.x;
    const int j  = bid >> 5;
    const int s  = (j < 8) ? j : 23 - j;             // strip pair (2s, 2s+1)
    const int bh = (bid & 7) * 4 + ((bid >> 3) & 3); // XCD-pinned (b,h)
    const int b = bh >> 4, h = bh & 15;
    const int strip  = 2 * s + ((w < 2) ? 1 : 0);    // this wave's 64-row strip
    const int lastkt = strip;                        // wave's diagonal k-tile
    const int ntiles = 2 * s + 2;                    // staged tiles
    const size_t rowbase = (size_t)b * TSEQ;
    const int qrow0 = strip * 64 + (w & 1) * 32;

    // Q fragments, pre-scaled by SC_LOG2E in gemm1
    bf16x8 qf[2][2];
#pragma unroll
    for (int mi = 0; mi < 2; mi++) {
        const unsigned short* qp =
            qkv + (rowbase + qrow0 + mi * 16 + lr) * 3072 + h * 64 + lg * 8;
        qf[mi][0] = *(const bf16x8*)qp;
        qf[mi][1] = *(const bf16x8*)(qp + 32);
    }

    // staging source pointers, fragment order
    const unsigned short* ksrc[2];
    const unsigned short* vsrc[2];
#pragma unroll
    for (int jj = 0; jj < 2; jj++) {
        const int d = tid + jj * 256;
        const int fr = (d >> 7) * 16 + (d & 15);
        const int cc = ((d >> 6) & 1) * 32 + ((d & 63) >> 4) * 8;
        ksrc[jj] = qkv + (rowbase + fr) * 3072 + 1024 + h * 64 + cc;
        vsrc[jj] = vtg + ((size_t)bh * 64 + fr) * TSEQ + cc;
    }

#define STAGE(kt_, bufi) do {                                      \
        const size_t ko_ = (size_t)(kt_) * 64 * 3072;              \
        const int vo_ = (kt_) * 64;                                \
        gld_lds16(ksrc[0] + ko_, &Ks[bufi][tid * 8]);              \
        gld_lds16(ksrc[1] + ko_, &Ks[bufi][tid * 8 + 2048]);       \
        gld_lds16(vsrc[0] + vo_, &Vs[bufi][tid * 8]);              \
        gld_lds16(vsrc[1] + vo_, &Vs[bufi][tid * 8 + 2048]);       \
    } while (0)

    f32x4 o[2][4] = {};
    float ps[2] = {0.f, 0.f};     // lane-local rsum partial for q = (mi, lr)
    unsigned short* pw = &Pl[w][0];

    STAGE(0, 0);
    __syncthreads();

    int cur = 0;
    for (int kt = 0; kt < ntiles; ++kt) {
        if (kt + 1 < ntiles) STAGE(kt + 1, cur ^ 1);

        if (kt <= lastkt) {   // wave-uniform: skip tiles past this strip's diag
            const unsigned short* kc = Ks[cur];
            const unsigned short* vc = Vs[cur];

            bf16x8 kb[4][2];
#pragma unroll
            for (int f = 0; f < 4; f++) {
                kb[f][0] = *(const bf16x8*)(kc + ((f * 2 + 0) * 64 + l) * 8);
                kb[f][1] = *(const bf16x8*)(kc + ((f * 2 + 1) * 64 + l) * 8);
            }

            // S^T = K Q^T (swapped operands): lane holds q=lr, k=f*16+lg*4+r
            float pvv[2][4][4];
            __builtin_amdgcn_s_setprio(1);
#pragma unroll
            for (int mi = 0; mi < 2; mi++)
#pragma unroll
                for (int f = 0; f < 4; f++) {
                    f32x4 z = {0.f, 0.f, 0.f, 0.f};
                    f32x4 sv = __builtin_amdgcn_mfma_f32_16x16x32_bf16(kb[f][0], qf[mi][0], z, 0, 0, 0);
                    sv = __builtin_amdgcn_mfma_f32_16x16x32_bf16(kb[f][1], qf[mi][1], sv, 0, 0, 0);
#pragma unroll
                    for (int r = 0; r < 4; r++) pvv[mi][f][r] = sv[r];
                }
            __builtin_amdgcn_s_setprio(0);

            if (kt == lastkt) {  // diagonal tile only: tril zeroing (exp2(0)=1)
#pragma unroll
                for (int mi = 0; mi < 2; mi++) {
                    const int qr = qrow0 + mi * 16 + lr;
#pragma unroll
                    for (int f = 0; f < 4; f++)
#pragma unroll
                        for (int r = 0; r < 4; r++) {
                            const int kcol = kt * 64 + f * 16 + lg * 4 + r;
                            if (kcol > qr) pvv[mi][f][r] = 0.f;
                        }
                }
            }

            // exp2 + lane-local rsum + cvt_pk + b64 pack to P tile
#pragma unroll
            for (int mi = 0; mi < 2; mi++)
#pragma unroll
                for (int f = 0; f < 4; f++) {
                    float p0 = EXP2F(pvv[mi][f][0]);
                    float p1 = EXP2F(pvv[mi][f][1]);
                    float p2 = EXP2F(pvv[mi][f][2]);
                    float p3 = EXP2F(pvv[mi][f][3]);
                    ps[mi] += (p0 + p1) + (p2 + p3);
                    uint2 pk;
                    pk.x = cvtpk_bf16(p0, p1);
                    pk.y = cvtpk_bf16(p2, p3);
                    *(uint2*)(pw + (mi * 16 + lr) * 72 + f * 16 + lg * 4) = pk;
                }

            bf16x8 pa[2][2];
#pragma unroll
            for (int mi = 0; mi < 2; mi++) {
                pa[mi][0] = *(const bf16x8*)(pw + (mi * 16 + lr) * 72 + lg * 8);
                pa[mi][1] = *(const bf16x8*)(pw + (mi * 16 + lr) * 72 + 32 + lg * 8);
            }
            bf16x8 vb[4][2];
#pragma unroll
            for (int f2 = 0; f2 < 4; f2++) {
                vb[f2][0] = *(const bf16x8*)(vc + ((f2 * 2 + 0) * 64 + l) * 8);
                vb[f2][1] = *(const bf16x8*)(vc + ((f2 * 2 + 1) * 64 + l) * 8);
            }
            __builtin_amdgcn_s_setprio(1);
#pragma unroll
            for (int mi = 0; mi < 2; mi++)
#pragma unroll
                for (int f2 = 0; f2 < 4; f2++) {
                    o[mi][f2] = __builtin_amdgcn_mfma_f32_16x16x32_bf16(pa[mi][0], vb[f2][0], o[mi][f2], 0, 0, 0);
                    o[mi][f2] = __builtin_amdgcn_mfma_f32_16x16x32_bf16(pa[mi][1], vb[f2][1], o[mi][f2], 0, 0, 0);
                }
            __builtin_amdgcn_s_setprio(0);
        }

        __syncthreads();
        cur ^= 1;
    }
#undef STAGE

    // rsum finalize: reduce across lg groups (lanes sharing lr)
#pragma unroll
    for (int mi = 0; mi < 2; mi++) {
        ps[mi] += __shfl_xor(ps[mi], 16);
        ps[mi] += __shfl_xor(ps[mi], 32);
    }
    // redistribute to o-row owners: row q = qrow0 + mi*16 + lg*4 + r
    float rget[2][4];
#pragma unroll
    for (int mi = 0; mi < 2; mi++)
#pragma unroll
        for (int r = 0; r < 4; r++)
            rget[mi][r] = __shfl(ps[mi], lg * 4 + r);

    // future-tile V column sums (vsuf folded in): tpv[f2] = sum_{t>strip}
    float tpv[4] = {0.f, 0.f, 0.f, 0.f};
    for (int t = lastkt + 1; t < 32; ++t) {
        const float* tsp = ts + ((size_t)bh * 32 + t) * 64 + lr;
#pragma unroll
        for (int f2 = 0; f2 < 4; f2++) tpv[f2] += tsp[f2 * 16];
    }

    // epilogue: closed-form future part, normalize, store
    const float nmask = (float)((31 - lastkt) * 64);
#pragma unroll
    for (int mi = 0; mi < 2; mi++)
#pragma unroll
        for (int r = 0; r < 4; r++) {
            const float inv = 1.f / (rget[mi][r] + nmask);
#pragma unroll
            for (int f2 = 0; f2 < 4; f2++) {
                float num = o[mi][f2][r] + tpv[f2];
                out[(rowbase + qrow0 + mi * 16 + lg * 4 + r) * 1024 + h * 64 + f2 * 16 + lr] =
                    f2bf(num * inv);
            }
        }
}

// ---------------------------------------------------------------------------
extern "C" void kernel_launch(void* const* d_in, const int* in_sizes, int n_in,
                              void* d_out, int out_size, void* d_ws, size_t ws_size,
                              hipStream_t stream) {
    const float* x     = (const float*)d_in[0];
    const float* w_in  = (const float*)d_in[1];
    const float* w_out = (const float*)d_in[2];

    unsigned short* ws  = (unsigned short*)d_ws;
    unsigned short* xb  = ws;                            // 4096*1024
    unsigned short* wib = xb  + (size_t)4096 * 1024;     // 3072*1024
    unsigned short* wob = wib + (size_t)3072 * 1024;     // 1024*1024
    unsigned short* qkv = wob + (size_t)1024 * 1024;     // 4096*3072
    unsigned short* ao  = qkv + (size_t)4096 * 3072;     // 4096*1024
    float* tsbuf = (float*)(ao + (size_t)4096 * 1024);   // 32*32*64 f32
    unsigned short* vtg = (unsigned short*)(tsbuf + 32 * 32 * 64); // 32*64*2048

    cast3_kernel<<<(NX4 + NWI4 + NWO4) / 256, 256, 0, stream>>>(
        x, w_in, w_out, xb, wib, wob);

    // gemm1: QKV + fused V-transpose (vtg) + fused V tile colsums (tsbuf)
    gemm_bt<0><<<(4096 / 128) * (3072 / 128), 256, 0, stream>>>(
        xb, wib, qkv, 4096, 3072, 1024, vtg, tsbuf);
    attn_kernel<<<512, 256, 0, stream>>>(qkv, vtg, tsbuf, ao);
    gemm_bt<1><<<(4096 / 128) * (1024 / 128), 256, 0, stream>>>(
        ao, wob, (float*)d_out, 4096, 1024, 1024, nullptr, nullptr);
}

// Round 15
// 103.610 us; speedup vs baseline: 1.2786x; 1.2786x over previous
//
#include <hip/hip_runtime.h>
#include <hip/hip_bf16.h>
#include <stdint.h>

// Problem constants
#define TSEQ   2048
#define DMODEL 1024
#define NHEAD  16
#define HDIM   64

typedef __attribute__((ext_vector_type(8))) __bf16 bf16x8;
typedef __attribute__((ext_vector_type(4))) float f32x4;
typedef __attribute__((ext_vector_type(8))) unsigned short u16x8;

// log2(e)/8 : folds the 1/sqrt(64) logit scale into exp2 (applied to Q in gemm1)
#define SC_LOG2E 0.18033688011112042f

#if __has_builtin(__builtin_amdgcn_exp2f)
#define EXP2F(x) __builtin_amdgcn_exp2f(x)
#else
#define EXP2F(x) __expf(0.6931471805599453f * (x))
#endif

__device__ __forceinline__ unsigned short f2bf(float f) {
    __hip_bfloat16 h = __float2bfloat16(f);
    return __builtin_bit_cast(unsigned short, h);
}
__device__ __forceinline__ float bf2f(unsigned short u) {
    union { unsigned int i; float f; } v;
    v.i = ((unsigned int)u) << 16;
    return v.f;
}
__device__ __forceinline__ unsigned int cvtpk_bf16(float lo, float hi) {
    unsigned int r;
    asm("v_cvt_pk_bf16_f32 %0, %1, %2" : "=v"(r) : "v"(lo), "v"(hi));
    return r;
}

__device__ __forceinline__ void gld_lds16(const void* g, void* s) {
    __builtin_amdgcn_global_load_lds(
        (__attribute__((address_space(1))) void*)(void*)g,
        (__attribute__((address_space(3))) void*)s, 16, 0, 0);
}

// ---------------------------------------------------------------------------
// fused fp32 -> bf16 cast for x, w_in, w_out (one launch)
// ---------------------------------------------------------------------------
#define NX4  (4096 * 1024 / 4)
#define NWI4 (3072 * 1024 / 4)
#define NWO4 (1024 * 1024 / 4)
__global__ void cast3_kernel(const float* __restrict__ x,
                             const float* __restrict__ wi,
                             const float* __restrict__ wo,
                             unsigned short* __restrict__ ox,
                             unsigned short* __restrict__ owi,
                             unsigned short* __restrict__ owo) {
    int i = blockIdx.x * blockDim.x + threadIdx.x;
    const float* s;
    unsigned short* d;
    int off;
    if (i < NX4)              { s = x;  d = ox;  off = i; }
    else if (i < NX4 + NWI4)  { s = wi; d = owi; off = i - NX4; }
    else                      { s = wo; d = owo; off = i - NX4 - NWI4; }
    float4 v = ((const float4*)s)[off];
    ushort4 u;
    u.x = f2bf(v.x); u.y = f2bf(v.y); u.z = f2bf(v.z); u.w = f2bf(v.w);
    ((ushort4*)d)[off] = u;
}

// ---------------------------------------------------------------------------
// GEMM: C[m,n] = sum_k A[m,k] * B[n,k]   (A:[M,K] bf16, B:[N,K] bf16)
// BK=64 row-major [128][64] LDS tile with XOR chunk-swizzle (T2, rule-21
// both-sides form): LDS(row,ch) = global(row, ch^(row&7)).
//  - STAGE: slot c -> row=c>>3, src chunk=(c&7)^(row&7). The 8 lanes of a
//    row source the SAME 128B segment (permuted) -> global coalescing kept.
//  - READ: fragment (row, kchunk) at LDS chunk kchunk^(lr&7) -> 64 lanes
//    spread 8-per-bank-quad = the ds_read_b128 floor (no conflicts).
// MFMA inputs bit-identical to the unswizzled layout.
// MODE 0 (QKV GEMM, N=3072): bn<8 -> Q stored *SC_LOG2E; bn in [8,16) -> K
//   plain; bn in [16,24) -> V written TRANSPOSED to vtg + colsums to ts.
// MODE 1 (out GEMM): f32 store to C.
// ---------------------------------------------------------------------------
template<int MODE>
__global__ __launch_bounds__(256, 3)
void gemm_bt(const unsigned short* __restrict__ A,
             const unsigned short* __restrict__ B,
             void* __restrict__ C, int M, int N, int K,
             unsigned short* __restrict__ vtg,
             float* __restrict__ ts) {
    (void)M;
    __shared__ unsigned short As[128 * 64];
    __shared__ unsigned short Bs[128 * 64];
    const int tid = threadIdx.x;
    const int nb = N >> 7;
    const int bm = blockIdx.x / nb;
    const int bn = blockIdx.x % nb;
    const int w  = tid >> 6, l = tid & 63;
    const int wr = w >> 1,  wc = w & 1;
    const int lr = l & 15,  lg = l >> 4;

    f32x4 acc[4][4] = {};

    const unsigned short* Ab = A + (size_t)bm * 128 * K;
    const unsigned short* Bb = B + (size_t)bn * 128 * K;

    // swizzled staging source pointers (kt added in the loop)
    const unsigned short* asrc[4];
    const unsigned short* bsrc[4];
#pragma unroll
    for (int j = 0; j < 4; j++) {
        const int c   = tid + j * 256;
        const int row = c >> 3;
        const int ch  = (c & 7) ^ (row & 7);
        asrc[j] = Ab + (size_t)row * K + ch * 8;
        bsrc[j] = Bb + (size_t)row * K + ch * 8;
    }
    // swizzled read chunk bases (elements): chunk kk*4+lg, xor lr&7
    const int sx = lr & 7;

    for (int kt = 0; kt < K; kt += 64) {
        __syncthreads();
#pragma unroll
        for (int j = 0; j < 4; j++)
            gld_lds16(asrc[j] + kt, As + (tid + j * 256) * 8);
#pragma unroll
        for (int j = 0; j < 4; j++)
            gld_lds16(bsrc[j] + kt, Bs + (tid + j * 256) * 8);
        __syncthreads();

#pragma unroll
        for (int kk = 0; kk < 2; kk++) {
            const int rch = ((kk * 4 + lg) ^ sx) * 8;
            bf16x8 af[4], bfr[4];
#pragma unroll
            for (int i = 0; i < 4; i++)
                af[i] = *(const bf16x8*)(As + (wr * 64 + i * 16 + lr) * 64 + rch);
#pragma unroll
            for (int i = 0; i < 4; i++)
                bfr[i] = *(const bf16x8*)(Bs + (wc * 64 + i * 16 + lr) * 64 + rch);
#pragma unroll
            for (int mi = 0; mi < 4; mi++)
#pragma unroll
                for (int ni = 0; ni < 4; ni++)
                    acc[mi][ni] = __builtin_amdgcn_mfma_f32_16x16x32_bf16(
                        af[mi], bfr[ni], acc[mi][ni], 0, 0, 0);
        }
    }

    const int row0 = bm * 128 + wr * 64;
    const int col0 = bn * 128 + wc * 64;

    if (MODE == 0 && bn >= 16) {
        // ---- fused V transpose + column sums ----
        const int h     = (bn - 16) * 2 + wc;
        const int krow0 = row0;                 // wave's 64 token rows
        const int bb    = krow0 >> 11;
        const int kloc0 = krow0 & 2047;
        const int bh    = bb * 16 + h;
        const int t     = kloc0 >> 6;
#pragma unroll
        for (int ni = 0; ni < 4; ni++) {
            const size_t dbase = ((size_t)(bh * 64 + ni * 16 + lr)) * TSEQ;
#pragma unroll
            for (int mi = 0; mi < 4; mi++) {
                uint2 pk;
                pk.x = cvtpk_bf16(acc[mi][ni][0], acc[mi][ni][1]);
                pk.y = cvtpk_bf16(acc[mi][ni][2], acc[mi][ni][3]);
                *(uint2*)(vtg + dbase + kloc0 + mi * 16 + lg * 4) = pk;
            }
        }
#pragma unroll
        for (int ni = 0; ni < 4; ni++) {
            float sum = 0.f;
#pragma unroll
            for (int mi = 0; mi < 4; mi++)
#pragma unroll
                for (int r = 0; r < 4; r++) sum += acc[mi][ni][r];
            sum += __shfl_xor(sum, 16);
            sum += __shfl_xor(sum, 32);
            if (lg == 0)
                ts[((size_t)bh * 32 + t) * 64 + ni * 16 + lr] = sum;
        }
        return;
    }

    const float qsc = (MODE == 0 && bn < 8) ? SC_LOG2E : 1.0f;
#pragma unroll
    for (int mi = 0; mi < 4; mi++)
#pragma unroll
        for (int ni = 0; ni < 4; ni++)
#pragma unroll
            for (int r = 0; r < 4; r++) {
                const int row = row0 + mi * 16 + lg * 4 + r;
                const int col = col0 + ni * 16 + lr;
                if (MODE == 1)
                    ((float*)C)[(size_t)row * N + col] = acc[mi][ni][r];
                else
                    ((unsigned short*)C)[(size_t)row * N + col] =
                        f2bf(acc[mi][ni][r] * qsc);
            }
}

// ---------------------------------------------------------------------------
// Attention v10 (R10-verified, FROZEN): consecutive strip pairs, 4-wave
// blocks, dbuf LDS K/V^T, plain __syncthreads, swapped QK^T
// (S^T = mfma(K,Q): lane holds q=lr, k=f*16+lg*4+r), cvt_pk P-pack,
// lane-local rsum, vsuf folded in epilogue.
// ---------------------------------------------------------------------------
__global__ __launch_bounds__(256, 2)
void attn_kernel(const unsigned short* __restrict__ qkv,
                 const unsigned short* __restrict__ vtg,
                 const float* __restrict__ ts,
                 unsigned short* __restrict__ out) {
    __shared__ __attribute__((aligned(16))) unsigned short Ks[2][4096];
    __shared__ __attribute__((aligned(16))) unsigned short Vs[2][4096];
    __shared__ __attribute__((aligned(16))) unsigned short Pl[4][32 * 72];

    const int tid = threadIdx.x;
    const int w = tid >> 6, l = tid & 63, lr = l & 15, lg = l >> 4;
    const int bid = blockIdx.x;
    const int j  = bid >> 5;
    const int s  = (j < 8) ? j : 23 - j;             // strip pair (2s, 2s+1)
    const int bh = (bid & 7) * 4 + ((bid >> 3) & 3); // XCD-pinned (b,h)
    const int b = bh >> 4, h = bh & 15;
    const int strip  = 2 * s + ((w < 2) ? 1 : 0);    // this wave's 64-row strip
    const int lastkt = strip;                        // wave's diagonal k-tile
    const int ntiles = 2 * s + 2;                    // staged tiles
    const size_t rowbase = (size_t)b * TSEQ;
    const int qrow0 = strip * 64 + (w & 1) * 32;

    // Q fragments, pre-scaled by SC_LOG2E in gemm1
    bf16x8 qf[2][2];
#pragma unroll
    for (int mi = 0; mi < 2; mi++) {
        const unsigned short* qp =
            qkv + (rowbase + qrow0 + mi * 16 + lr) * 3072 + h * 64 + lg * 8;
        qf[mi][0] = *(const bf16x8*)qp;
        qf[mi][1] = *(const bf16x8*)(qp + 32);
    }

    // staging source pointers, fragment order
    const unsigned short* ksrc[2];
    const unsigned short* vsrc[2];
#pragma unroll
    for (int jj = 0; jj < 2; jj++) {
        const int d = tid + jj * 256;
        const int fr = (d >> 7) * 16 + (d & 15);
        const int cc = ((d >> 6) & 1) * 32 + ((d & 63) >> 4) * 8;
        ksrc[jj] = qkv + (rowbase + fr) * 3072 + 1024 + h * 64 + cc;
        vsrc[jj] = vtg + ((size_t)bh * 64 + fr) * TSEQ + cc;
    }

#define STAGE(kt_, bufi) do {                                      \
        const size_t ko_ = (size_t)(kt_) * 64 * 3072;              \
        const int vo_ = (kt_) * 64;                                \
        gld_lds16(ksrc[0] + ko_, &Ks[bufi][tid * 8]);              \
        gld_lds16(ksrc[1] + ko_, &Ks[bufi][tid * 8 + 2048]);       \
        gld_lds16(vsrc[0] + vo_, &Vs[bufi][tid * 8]);              \
        gld_lds16(vsrc[1] + vo_, &Vs[bufi][tid * 8 + 2048]);       \
    } while (0)

    f32x4 o[2][4] = {};
    float ps[2] = {0.f, 0.f};     // lane-local rsum partial for q = (mi, lr)
    unsigned short* pw = &Pl[w][0];

    STAGE(0, 0);
    __syncthreads();

    int cur = 0;
    for (int kt = 0; kt < ntiles; ++kt) {
        if (kt + 1 < ntiles) STAGE(kt + 1, cur ^ 1);

        if (kt <= lastkt) {   // wave-uniform: skip tiles past this strip's diag
            const unsigned short* kc = Ks[cur];
            const unsigned short* vc = Vs[cur];

            bf16x8 kb[4][2];
#pragma unroll
            for (int f = 0; f < 4; f++) {
                kb[f][0] = *(const bf16x8*)(kc + ((f * 2 + 0) * 64 + l) * 8);
                kb[f][1] = *(const bf16x8*)(kc + ((f * 2 + 1) * 64 + l) * 8);
            }

            // S^T = K Q^T (swapped operands): lane holds q=lr, k=f*16+lg*4+r
            float pvv[2][4][4];
            __builtin_amdgcn_s_setprio(1);
#pragma unroll
            for (int mi = 0; mi < 2; mi++)
#pragma unroll
                for (int f = 0; f < 4; f++) {
                    f32x4 z = {0.f, 0.f, 0.f, 0.f};
                    f32x4 sv = __builtin_amdgcn_mfma_f32_16x16x32_bf16(kb[f][0], qf[mi][0], z, 0, 0, 0);
                    sv = __builtin_amdgcn_mfma_f32_16x16x32_bf16(kb[f][1], qf[mi][1], sv, 0, 0, 0);
#pragma unroll
                    for (int r = 0; r < 4; r++) pvv[mi][f][r] = sv[r];
                }
            __builtin_amdgcn_s_setprio(0);

            if (kt == lastkt) {  // diagonal tile only: tril zeroing (exp2(0)=1)
#pragma unroll
                for (int mi = 0; mi < 2; mi++) {
                    const int qr = qrow0 + mi * 16 + lr;
#pragma unroll
                    for (int f = 0; f < 4; f++)
#pragma unroll
                        for (int r = 0; r < 4; r++) {
                            const int kcol = kt * 64 + f * 16 + lg * 4 + r;
                            if (kcol > qr) pvv[mi][f][r] = 0.f;
                        }
                }
            }

            // exp2 + lane-local rsum + cvt_pk + b64 pack to P tile
#pragma unroll
            for (int mi = 0; mi < 2; mi++)
#pragma unroll
                for (int f = 0; f < 4; f++) {
                    float p0 = EXP2F(pvv[mi][f][0]);
                    float p1 = EXP2F(pvv[mi][f][1]);
                    float p2 = EXP2F(pvv[mi][f][2]);
                    float p3 = EXP2F(pvv[mi][f][3]);
                    ps[mi] += (p0 + p1) + (p2 + p3);
                    uint2 pk;
                    pk.x = cvtpk_bf16(p0, p1);
                    pk.y = cvtpk_bf16(p2, p3);
                    *(uint2*)(pw + (mi * 16 + lr) * 72 + f * 16 + lg * 4) = pk;
                }

            bf16x8 pa[2][2];
#pragma unroll
            for (int mi = 0; mi < 2; mi++) {
                pa[mi][0] = *(const bf16x8*)(pw + (mi * 16 + lr) * 72 + lg * 8);
                pa[mi][1] = *(const bf16x8*)(pw + (mi * 16 + lr) * 72 + 32 + lg * 8);
            }
            bf16x8 vb[4][2];
#pragma unroll
            for (int f2 = 0; f2 < 4; f2++) {
                vb[f2][0] = *(const bf16x8*)(vc + ((f2 * 2 + 0) * 64 + l) * 8);
                vb[f2][1] = *(const bf16x8*)(vc + ((f2 * 2 + 1) * 64 + l) * 8);
            }
            __builtin_amdgcn_s_setprio(1);
#pragma unroll
            for (int mi = 0; mi < 2; mi++)
#pragma unroll
                for (int f2 = 0; f2 < 4; f2++) {
                    o[mi][f2] = __builtin_amdgcn_mfma_f32_16x16x32_bf16(pa[mi][0], vb[f2][0], o[mi][f2], 0, 0, 0);
                    o[mi][f2] = __builtin_amdgcn_mfma_f32_16x16x32_bf16(pa[mi][1], vb[f2][1], o[mi][f2], 0, 0, 0);
                }
            __builtin_amdgcn_s_setprio(0);
        }

        __syncthreads();
        cur ^= 1;
    }
#undef STAGE

    // rsum finalize: reduce across lg groups (lanes sharing lr)
#pragma unroll
    for (int mi = 0; mi < 2; mi++) {
        ps[mi] += __shfl_xor(ps[mi], 16);
        ps[mi] += __shfl_xor(ps[mi], 32);
    }
    // redistribute to o-row owners: row q = qrow0 + mi*16 + lg*4 + r
    float rget[2][4];
#pragma unroll
    for (int mi = 0; mi < 2; mi++)
#pragma unroll
        for (int r = 0; r < 4; r++)
            rget[mi][r] = __shfl(ps[mi], lg * 4 + r);

    // future-tile V column sums (vsuf folded in): tpv[f2] = sum_{t>strip}
    float tpv[4] = {0.f, 0.f, 0.f, 0.f};
    for (int t = lastkt + 1; t < 32; ++t) {
        const float* tsp = ts + ((size_t)bh * 32 + t) * 64 + lr;
#pragma unroll
        for (int f2 = 0; f2 < 4; f2++) tpv[f2] += tsp[f2 * 16];
    }

    // epilogue: closed-form future part, normalize, store
    const float nmask = (float)((31 - lastkt) * 64);
#pragma unroll
    for (int mi = 0; mi < 2; mi++)
#pragma unroll
        for (int r = 0; r < 4; r++) {
            const float inv = 1.f / (rget[mi][r] + nmask);
#pragma unroll
            for (int f2 = 0; f2 < 4; f2++) {
                float num = o[mi][f2][r] + tpv[f2];
                out[(rowbase + qrow0 + mi * 16 + lg * 4 + r) * 1024 + h * 64 + f2 * 16 + lr] =
                    f2bf(num * inv);
            }
        }
}

// ---------------------------------------------------------------------------
extern "C" void kernel_launch(void* const* d_in, const int* in_sizes, int n_in,
                              void* d_out, int out_size, void* d_ws, size_t ws_size,
                              hipStream_t stream) {
    const float* x     = (const float*)d_in[0];
    const float* w_in  = (const float*)d_in[1];
    const float* w_out = (const float*)d_in[2];

    unsigned short* ws  = (unsigned short*)d_ws;
    unsigned short* xb  = ws;                            // 4096*1024
    unsigned short* wib = xb  + (size_t)4096 * 1024;     // 3072*1024
    unsigned short* wob = wib + (size_t)3072 * 1024;     // 1024*1024
    unsigned short* qkv = wob + (size_t)1024 * 1024;     // 4096*3072
    unsigned short* ao  = qkv + (size_t)4096 * 3072;     // 4096*1024
    float* tsbuf = (float*)(ao + (size_t)4096 * 1024);   // 32*32*64 f32
    unsigned short* vtg = (unsigned short*)(tsbuf + 32 * 32 * 64); // 32*64*2048

    cast3_kernel<<<(NX4 + NWI4 + NWO4) / 256, 256, 0, stream>>>(
        x, w_in, w_out, xb, wib, wob);

    // gemm1: QKV + fused V-transpose (vtg) + fused V tile colsums (tsbuf)
    gemm_bt<0><<<(4096 / 128) * (3072 / 128), 256, 0, stream>>>(
        xb, wib, qkv, 4096, 3072, 1024, vtg, tsbuf);
    attn_kernel<<<512, 256, 0, stream>>>(qkv, vtg, tsbuf, ao);
    gemm_bt<1><<<(4096 / 128) * (1024 / 128), 256, 0, stream>>>(
        ao, wob, (float*)d_out, 4096, 1024, 1024, nullptr, nullptr);
}

// Round 16
// 99.137 us; speedup vs baseline: 1.3363x; 1.0451x over previous
//
#include <hip/hip_runtime.h>
#include <hip/hip_bf16.h>
#include <stdint.h>

// Problem constants
#define TSEQ   2048
#define DMODEL 1024
#define NHEAD  16
#define HDIM   64

typedef __attribute__((ext_vector_type(8))) __bf16 bf16x8;
typedef __attribute__((ext_vector_type(4))) float f32x4;
typedef __attribute__((ext_vector_type(8))) unsigned short u16x8;

// log2(e)/8 : folds the 1/sqrt(64) logit scale into exp2 (applied to Q in gemm1)
#define SC_LOG2E 0.18033688011112042f

#if __has_builtin(__builtin_amdgcn_exp2f)
#define EXP2F(x) __builtin_amdgcn_exp2f(x)
#else
#define EXP2F(x) __expf(0.6931471805599453f * (x))
#endif

__device__ __forceinline__ unsigned short f2bf(float f) {
    __hip_bfloat16 h = __float2bfloat16(f);
    return __builtin_bit_cast(unsigned short, h);
}
__device__ __forceinline__ float bf2f(unsigned short u) {
    union { unsigned int i; float f; } v;
    v.i = ((unsigned int)u) << 16;
    return v.f;
}
__device__ __forceinline__ unsigned int cvtpk_bf16(float lo, float hi) {
    unsigned int r;
    asm("v_cvt_pk_bf16_f32 %0, %1, %2" : "=v"(r) : "v"(lo), "v"(hi));
    return r;
}

__device__ __forceinline__ void gld_lds16(const void* g, void* s) {
    __builtin_amdgcn_global_load_lds(
        (__attribute__((address_space(1))) void*)(void*)g,
        (__attribute__((address_space(3))) void*)s, 16, 0, 0);
}

// ---------------------------------------------------------------------------
// fused fp32 -> bf16 cast for x, w_in, w_out (one launch)
// ---------------------------------------------------------------------------
#define NX4  (4096 * 1024 / 4)
#define NWI4 (3072 * 1024 / 4)
#define NWO4 (1024 * 1024 / 4)
__global__ void cast3_kernel(const float* __restrict__ x,
                             const float* __restrict__ wi,
                             const float* __restrict__ wo,
                             unsigned short* __restrict__ ox,
                             unsigned short* __restrict__ owi,
                             unsigned short* __restrict__ owo) {
    int i = blockIdx.x * blockDim.x + threadIdx.x;
    const float* s;
    unsigned short* d;
    int off;
    if (i < NX4)              { s = x;  d = ox;  off = i; }
    else if (i < NX4 + NWI4)  { s = wi; d = owi; off = i - NX4; }
    else                      { s = wo; d = owo; off = i - NX4 - NWI4; }
    float4 v = ((const float4*)s)[off];
    ushort4 u;
    u.x = f2bf(v.x); u.y = f2bf(v.y); u.z = f2bf(v.z); u.w = f2bf(v.w);
    ((ushort4*)d)[off] = u;
}

// ---------------------------------------------------------------------------
// GEMM: C[m,n] = sum_k A[m,k] * B[n,k]   (A:[M,K] bf16, B:[N,K] bf16)
// Template MR = A-row fragments per wave (BM = MR*32; wave = MR*16 x 64).
//   MR=4: 128x128 tile (gemm1).  MR=2: 64x128 tile (gemm2 -> 512 blocks,
//   2 blocks/CU instead of 1 -> cross-block barrier overlap, m114).
// BK=64 row-major LDS tile with XOR chunk-swizzle (T2, rule-21 both-sides):
//   LDS(row,ch) = global(row, ch^(row&7)); stage keeps 128B-coalescing,
//   read spreads lanes 8-per-bank-quad (conflict-free, R15-verified: 0).
// MODE 0 (QKV GEMM, N=3072): bn<8 -> Q stored *SC_LOG2E; bn in [8,16) -> K
//   plain; bn in [16,24) -> V written TRANSPOSED to vtg + colsums to ts.
// MODE 1 (out GEMM): f32 store to C.
// ---------------------------------------------------------------------------
template<int MODE, int MR>
__global__ __launch_bounds__(256, 3)
void gemm_bt(const unsigned short* __restrict__ A,
             const unsigned short* __restrict__ B,
             void* __restrict__ C, int M, int N, int K,
             unsigned short* __restrict__ vtg,
             float* __restrict__ ts) {
    (void)M;
    __shared__ unsigned short As[MR * 32 * 64];
    __shared__ unsigned short Bs[128 * 64];
    const int tid = threadIdx.x;
    const int nb = N >> 7;
    const int bm = blockIdx.x / nb;
    const int bn = blockIdx.x % nb;
    const int w  = tid >> 6, l = tid & 63;
    const int wr = w >> 1,  wc = w & 1;
    const int lr = l & 15,  lg = l >> 4;

    f32x4 acc[MR][4] = {};

    const unsigned short* Ab = A + (size_t)bm * (MR * 32) * K;
    const unsigned short* Bb = B + (size_t)bn * 128 * K;

    // swizzled staging source pointers (kt added in the loop)
    const unsigned short* asrc[MR];
    const unsigned short* bsrc[4];
#pragma unroll
    for (int j = 0; j < MR; j++) {
        const int c   = tid + j * 256;
        const int row = c >> 3;
        const int ch  = (c & 7) ^ (row & 7);
        asrc[j] = Ab + (size_t)row * K + ch * 8;
    }
#pragma unroll
    for (int j = 0; j < 4; j++) {
        const int c   = tid + j * 256;
        const int row = c >> 3;
        const int ch  = (c & 7) ^ (row & 7);
        bsrc[j] = Bb + (size_t)row * K + ch * 8;
    }
    // swizzled read chunk base: chunk kk*4+lg, xor lr&7
    const int sx = lr & 7;

    for (int kt = 0; kt < K; kt += 64) {
        __syncthreads();
#pragma unroll
        for (int j = 0; j < MR; j++)
            gld_lds16(asrc[j] + kt, As + (tid + j * 256) * 8);
#pragma unroll
        for (int j = 0; j < 4; j++)
            gld_lds16(bsrc[j] + kt, Bs + (tid + j * 256) * 8);
        __syncthreads();

#pragma unroll
        for (int kk = 0; kk < 2; kk++) {
            const int rch = ((kk * 4 + lg) ^ sx) * 8;
            bf16x8 af[MR], bfr[4];
#pragma unroll
            for (int i = 0; i < MR; i++)
                af[i] = *(const bf16x8*)(As + (wr * (MR * 16) + i * 16 + lr) * 64 + rch);
#pragma unroll
            for (int i = 0; i < 4; i++)
                bfr[i] = *(const bf16x8*)(Bs + (wc * 64 + i * 16 + lr) * 64 + rch);
#pragma unroll
            for (int mi = 0; mi < MR; mi++)
#pragma unroll
                for (int ni = 0; ni < 4; ni++)
                    acc[mi][ni] = __builtin_amdgcn_mfma_f32_16x16x32_bf16(
                        af[mi], bfr[ni], acc[mi][ni], 0, 0, 0);
        }
    }

    const int row0 = bm * (MR * 32) + wr * (MR * 16);
    const int col0 = bn * 128 + wc * 64;

    if (MODE == 0 && bn >= 16) {
        // ---- fused V transpose + column sums (MR==4: wave = 64 token rows) ----
        const int h     = (bn - 16) * 2 + wc;
        const int krow0 = row0;
        const int bb    = krow0 >> 11;
        const int kloc0 = krow0 & 2047;
        const int bh    = bb * 16 + h;
        const int t     = kloc0 >> 6;
#pragma unroll
        for (int ni = 0; ni < 4; ni++) {
            const size_t dbase = ((size_t)(bh * 64 + ni * 16 + lr)) * TSEQ;
#pragma unroll
            for (int mi = 0; mi < MR; mi++) {
                uint2 pk;
                pk.x = cvtpk_bf16(acc[mi][ni][0], acc[mi][ni][1]);
                pk.y = cvtpk_bf16(acc[mi][ni][2], acc[mi][ni][3]);
                *(uint2*)(vtg + dbase + kloc0 + mi * 16 + lg * 4) = pk;
            }
        }
#pragma unroll
        for (int ni = 0; ni < 4; ni++) {
            float sum = 0.f;
#pragma unroll
            for (int mi = 0; mi < MR; mi++)
#pragma unroll
                for (int r = 0; r < 4; r++) sum += acc[mi][ni][r];
            sum += __shfl_xor(sum, 16);
            sum += __shfl_xor(sum, 32);
            if (lg == 0)
                ts[((size_t)bh * 32 + t) * 64 + ni * 16 + lr] = sum;
        }
        return;
    }

    const float qsc = (MODE == 0 && bn < 8) ? SC_LOG2E : 1.0f;
#pragma unroll
    for (int mi = 0; mi < MR; mi++)
#pragma unroll
        for (int ni = 0; ni < 4; ni++)
#pragma unroll
            for (int r = 0; r < 4; r++) {
                const int row = row0 + mi * 16 + lg * 4 + r;
                const int col = col0 + ni * 16 + lr;
                if (MODE == 1)
                    ((float*)C)[(size_t)row * N + col] = acc[mi][ni][r];
                else
                    ((unsigned short*)C)[(size_t)row * N + col] =
                        f2bf(acc[mi][ni][r] * qsc);
            }
}

// ---------------------------------------------------------------------------
// Attention v10 (R10-verified, FROZEN): consecutive strip pairs, 4-wave
// blocks, dbuf LDS K/V^T, plain __syncthreads, swapped QK^T
// (S^T = mfma(K,Q): lane holds q=lr, k=f*16+lg*4+r), cvt_pk P-pack,
// lane-local rsum, vsuf folded in epilogue.
// ---------------------------------------------------------------------------
__global__ __launch_bounds__(256, 2)
void attn_kernel(const unsigned short* __restrict__ qkv,
                 const unsigned short* __restrict__ vtg,
                 const float* __restrict__ ts,
                 unsigned short* __restrict__ out) {
    __shared__ __attribute__((aligned(16))) unsigned short Ks[2][4096];
    __shared__ __attribute__((aligned(16))) unsigned short Vs[2][4096];
    __shared__ __attribute__((aligned(16))) unsigned short Pl[4][32 * 72];

    const int tid = threadIdx.x;
    const int w = tid >> 6, l = tid & 63, lr = l & 15, lg = l >> 4;
    const int bid = blockIdx.x;
    const int j  = bid >> 5;
    const int s  = (j < 8) ? j : 23 - j;             // strip pair (2s, 2s+1)
    const int bh = (bid & 7) * 4 + ((bid >> 3) & 3); // XCD-pinned (b,h)
    const int b = bh >> 4, h = bh & 15;
    const int strip  = 2 * s + ((w < 2) ? 1 : 0);    // this wave's 64-row strip
    const int lastkt = strip;                        // wave's diagonal k-tile
    const int ntiles = 2 * s + 2;                    // staged tiles
    const size_t rowbase = (size_t)b * TSEQ;
    const int qrow0 = strip * 64 + (w & 1) * 32;

    // Q fragments, pre-scaled by SC_LOG2E in gemm1
    bf16x8 qf[2][2];
#pragma unroll
    for (int mi = 0; mi < 2; mi++) {
        const unsigned short* qp =
            qkv + (rowbase + qrow0 + mi * 16 + lr) * 3072 + h * 64 + lg * 8;
        qf[mi][0] = *(const bf16x8*)qp;
        qf[mi][1] = *(const bf16x8*)(qp + 32);
    }

    // staging source pointers, fragment order
    const unsigned short* ksrc[2];
    const unsigned short* vsrc[2];
#pragma unroll
    for (int jj = 0; jj < 2; jj++) {
        const int d = tid + jj * 256;
        const int fr = (d >> 7) * 16 + (d & 15);
        const int cc = ((d >> 6) & 1) * 32 + ((d & 63) >> 4) * 8;
        ksrc[jj] = qkv + (rowbase + fr) * 3072 + 1024 + h * 64 + cc;
        vsrc[jj] = vtg + ((size_t)bh * 64 + fr) * TSEQ + cc;
    }

#define STAGE(kt_, bufi) do {                                      \
        const size_t ko_ = (size_t)(kt_) * 64 * 3072;              \
        const int vo_ = (kt_) * 64;                                \
        gld_lds16(ksrc[0] + ko_, &Ks[bufi][tid * 8]);              \
        gld_lds16(ksrc[1] + ko_, &Ks[bufi][tid * 8 + 2048]);       \
        gld_lds16(vsrc[0] + vo_, &Vs[bufi][tid * 8]);              \
        gld_lds16(vsrc[1] + vo_, &Vs[bufi][tid * 8 + 2048]);       \
    } while (0)

    f32x4 o[2][4] = {};
    float ps[2] = {0.f, 0.f};     // lane-local rsum partial for q = (mi, lr)
    unsigned short* pw = &Pl[w][0];

    STAGE(0, 0);
    __syncthreads();

    int cur = 0;
    for (int kt = 0; kt < ntiles; ++kt) {
        if (kt + 1 < ntiles) STAGE(kt + 1, cur ^ 1);

        if (kt <= lastkt) {   // wave-uniform: skip tiles past this strip's diag
            const unsigned short* kc = Ks[cur];
            const unsigned short* vc = Vs[cur];

            bf16x8 kb[4][2];
#pragma unroll
            for (int f = 0; f < 4; f++) {
                kb[f][0] = *(const bf16x8*)(kc + ((f * 2 + 0) * 64 + l) * 8);
                kb[f][1] = *(const bf16x8*)(kc + ((f * 2 + 1) * 64 + l) * 8);
            }

            // S^T = K Q^T (swapped operands): lane holds q=lr, k=f*16+lg*4+r
            float pvv[2][4][4];
            __builtin_amdgcn_s_setprio(1);
#pragma unroll
            for (int mi = 0; mi < 2; mi++)
#pragma unroll
                for (int f = 0; f < 4; f++) {
                    f32x4 z = {0.f, 0.f, 0.f, 0.f};
                    f32x4 sv = __builtin_amdgcn_mfma_f32_16x16x32_bf16(kb[f][0], qf[mi][0], z, 0, 0, 0);
                    sv = __builtin_amdgcn_mfma_f32_16x16x32_bf16(kb[f][1], qf[mi][1], sv, 0, 0, 0);
#pragma unroll
                    for (int r = 0; r < 4; r++) pvv[mi][f][r] = sv[r];
                }
            __builtin_amdgcn_s_setprio(0);

            if (kt == lastkt) {  // diagonal tile only: tril zeroing (exp2(0)=1)
#pragma unroll
                for (int mi = 0; mi < 2; mi++) {
                    const int qr = qrow0 + mi * 16 + lr;
#pragma unroll
                    for (int f = 0; f < 4; f++)
#pragma unroll
                        for (int r = 0; r < 4; r++) {
                            const int kcol = kt * 64 + f * 16 + lg * 4 + r;
                            if (kcol > qr) pvv[mi][f][r] = 0.f;
                        }
                }
            }

            // exp2 + lane-local rsum + cvt_pk + b64 pack to P tile
#pragma unroll
            for (int mi = 0; mi < 2; mi++)
#pragma unroll
                for (int f = 0; f < 4; f++) {
                    float p0 = EXP2F(pvv[mi][f][0]);
                    float p1 = EXP2F(pvv[mi][f][1]);
                    float p2 = EXP2F(pvv[mi][f][2]);
                    float p3 = EXP2F(pvv[mi][f][3]);
                    ps[mi] += (p0 + p1) + (p2 + p3);
                    uint2 pk;
                    pk.x = cvtpk_bf16(p0, p1);
                    pk.y = cvtpk_bf16(p2, p3);
                    *(uint2*)(pw + (mi * 16 + lr) * 72 + f * 16 + lg * 4) = pk;
                }

            bf16x8 pa[2][2];
#pragma unroll
            for (int mi = 0; mi < 2; mi++) {
                pa[mi][0] = *(const bf16x8*)(pw + (mi * 16 + lr) * 72 + lg * 8);
                pa[mi][1] = *(const bf16x8*)(pw + (mi * 16 + lr) * 72 + 32 + lg * 8);
            }
            bf16x8 vb[4][2];
#pragma unroll
            for (int f2 = 0; f2 < 4; f2++) {
                vb[f2][0] = *(const bf16x8*)(vc + ((f2 * 2 + 0) * 64 + l) * 8);
                vb[f2][1] = *(const bf16x8*)(vc + ((f2 * 2 + 1) * 64 + l) * 8);
            }
            __builtin_amdgcn_s_setprio(1);
#pragma unroll
            for (int mi = 0; mi < 2; mi++)
#pragma unroll
                for (int f2 = 0; f2 < 4; f2++) {
                    o[mi][f2] = __builtin_amdgcn_mfma_f32_16x16x32_bf16(pa[mi][0], vb[f2][0], o[mi][f2], 0, 0, 0);
                    o[mi][f2] = __builtin_amdgcn_mfma_f32_16x16x32_bf16(pa[mi][1], vb[f2][1], o[mi][f2], 0, 0, 0);
                }
            __builtin_amdgcn_s_setprio(0);
        }

        __syncthreads();
        cur ^= 1;
    }
#undef STAGE

    // rsum finalize: reduce across lg groups (lanes sharing lr)
#pragma unroll
    for (int mi = 0; mi < 2; mi++) {
        ps[mi] += __shfl_xor(ps[mi], 16);
        ps[mi] += __shfl_xor(ps[mi], 32);
    }
    // redistribute to o-row owners: row q = qrow0 + mi*16 + lg*4 + r
    float rget[2][4];
#pragma unroll
    for (int mi = 0; mi < 2; mi++)
#pragma unroll
        for (int r = 0; r < 4; r++)
            rget[mi][r] = __shfl(ps[mi], lg * 4 + r);

    // future-tile V column sums (vsuf folded in): tpv[f2] = sum_{t>strip}
    float tpv[4] = {0.f, 0.f, 0.f, 0.f};
    for (int t = lastkt + 1; t < 32; ++t) {
        const float* tsp = ts + ((size_t)bh * 32 + t) * 64 + lr;
#pragma unroll
        for (int f2 = 0; f2 < 4; f2++) tpv[f2] += tsp[f2 * 16];
    }

    // epilogue: closed-form future part, normalize, store
    const float nmask = (float)((31 - lastkt) * 64);
#pragma unroll
    for (int mi = 0; mi < 2; mi++)
#pragma unroll
        for (int r = 0; r < 4; r++) {
            const float inv = 1.f / (rget[mi][r] + nmask);
#pragma unroll
            for (int f2 = 0; f2 < 4; f2++) {
                float num = o[mi][f2][r] + tpv[f2];
                out[(rowbase + qrow0 + mi * 16 + lg * 4 + r) * 1024 + h * 64 + f2 * 16 + lr] =
                    f2bf(num * inv);
            }
        }
}

// ---------------------------------------------------------------------------
extern "C" void kernel_launch(void* const* d_in, const int* in_sizes, int n_in,
                              void* d_out, int out_size, void* d_ws, size_t ws_size,
                              hipStream_t stream) {
    const float* x     = (const float*)d_in[0];
    const float* w_in  = (const float*)d_in[1];
    const float* w_out = (const float*)d_in[2];

    unsigned short* ws  = (unsigned short*)d_ws;
    unsigned short* xb  = ws;                            // 4096*1024
    unsigned short* wib = xb  + (size_t)4096 * 1024;     // 3072*1024
    unsigned short* wob = wib + (size_t)3072 * 1024;     // 1024*1024
    unsigned short* qkv = wob + (size_t)1024 * 1024;     // 4096*3072
    unsigned short* ao  = qkv + (size_t)4096 * 3072;     // 4096*1024
    float* tsbuf = (float*)(ao + (size_t)4096 * 1024);   // 32*32*64 f32
    unsigned short* vtg = (unsigned short*)(tsbuf + 32 * 32 * 64); // 32*64*2048

    cast3_kernel<<<(NX4 + NWI4 + NWO4) / 256, 256, 0, stream>>>(
        x, w_in, w_out, xb, wib, wob);

    // gemm1: QKV + fused V-transpose (vtg) + fused V tile colsums (tsbuf)
    gemm_bt<0, 4><<<(4096 / 128) * (3072 / 128), 256, 0, stream>>>(
        xb, wib, qkv, 4096, 3072, 1024, vtg, tsbuf);
    attn_kernel<<<512, 256, 0, stream>>>(qkv, vtg, tsbuf, ao);
    // gemm2: 64x128 tile -> 512 blocks = 2 blocks/CU (barrier overlap)
    gemm_bt<1, 2><<<(4096 / 64) * (1024 / 128), 256, 0, stream>>>(
        ao, wob, (float*)d_out, 4096, 1024, 1024, nullptr, nullptr);
}